// Round 1
// baseline (3043.533 us; speedup 1.0000x reference)
//
#include <hip/hip_runtime.h>

// Problem constants
#define BATCH 32
#define CDIM 256
#define HW 4096            // 64*64
#define NVEC 131072        // BATCH*HW
#define NE 1024
#define DECAY 0.99f
#define ONE_MINUS_DECAY 0.01f
#define EPSV 1e-5f
#define ZQ_ELEMS 33554432  // BATCH*CDIM*HW

// ---------------- K1: embedding row squared norms ----------------
__global__ __launch_bounds__(256) void enorm_kernel(
    const float* __restrict__ emb, float* __restrict__ enorm) {
  int gid  = blockIdx.x * 256 + threadIdx.x;
  int e    = gid >> 6;          // wave index = embedding row
  int lane = threadIdx.x & 63;
  const float4* row = (const float4*)(emb + ((size_t)e << 8));
  float4 v = row[lane];
  float s = v.x * v.x + v.y * v.y + v.z * v.z + v.w * v.w;
  #pragma unroll
  for (int off = 32; off > 0; off >>= 1) s += __shfl_down(s, off);
  if (lane == 0) enorm[e] = s;
}

// ---------------- K2: argmin over codebook + counts + idx outputs ----------------
#define ET 64   // embedding tile (accumulators in VGPRs)
#define KC 16   // k chunk held in registers
__global__ __launch_bounds__(256) void argmin_kernel(
    const float* __restrict__ z, const float* __restrict__ emb,
    const float* __restrict__ enorm, int* __restrict__ idx_ws,
    float* __restrict__ idx_out, float* __restrict__ counts) {
  int n  = blockIdx.x * 256 + threadIdx.x;
  int b  = n >> 12;
  int hw = n & 4095;
  const float* zp = z + ((size_t)b << 20) + hw;  // element k at zp[k*4096]

  float best = 3.0e38f;
  int bi = 0;

  #pragma unroll 1
  for (int et = 0; et < NE; et += ET) {
    float acc[ET];
    #pragma unroll
    for (int e = 0; e < ET; ++e) acc[e] = 0.0f;

    #pragma unroll 1
    for (int k0 = 0; k0 < CDIM; k0 += KC) {
      float zreg[KC];
      #pragma unroll
      for (int kk = 0; kk < KC; ++kk)
        zreg[kk] = zp[(size_t)(k0 + kk) << 12];

      #pragma unroll
      for (int e = 0; e < ET; ++e) {
        const float* er = emb + (((size_t)(et + e)) << 8) + k0;
        float s0 = 0.f, s1 = 0.f, s2 = 0.f, s3 = 0.f;
        #pragma unroll
        for (int kk = 0; kk < KC; kk += 4) {
          s0 += zreg[kk + 0] * er[kk + 0];
          s1 += zreg[kk + 1] * er[kk + 1];
          s2 += zreg[kk + 2] * er[kk + 2];
          s3 += zreg[kk + 3] * er[kk + 3];
        }
        acc[e] += (s0 + s1) + (s2 + s3);
      }
    }

    #pragma unroll
    for (int e = 0; e < ET; ++e) {
      float d = enorm[et + e] - 2.0f * acc[e];
      if (d < best) { best = d; bi = et + e; }  // strict < : first-min tie-break
    }
  }

  idx_ws[n] = bi;
  idx_out[n] = (float)bi;
  atomicAdd(&counts[bi], 1.0f);
}

// ---------------- K3: z_q gather (NCHW) + loss partial ----------------
__global__ __launch_bounds__(256) void zq_loss_kernel(
    const float* __restrict__ z, const float* __restrict__ emb,
    const int* __restrict__ idx_ws, float* __restrict__ zq_out,
    float* __restrict__ loss_acc) {
  int stride = gridDim.x * 256;
  float lsum = 0.0f;
  for (int o = blockIdx.x * 256 + threadIdx.x; o < ZQ_ELEMS; o += stride) {
    int hw = o & 4095;
    int c  = (o >> 12) & 255;
    int b  = o >> 20;
    int e  = idx_ws[(b << 12) | hw];
    float q = emb[((size_t)e << 8) + c];
    zq_out[o] = q;
    float d = q - z[o];
    lsum += d * d;
  }
  __shared__ float red[256];
  red[threadIdx.x] = lsum;
  __syncthreads();
  for (int s = 128; s > 0; s >>= 1) {
    if (threadIdx.x < s) red[threadIdx.x] += red[threadIdx.x + s];
    __syncthreads();
  }
  if (threadIdx.x == 0) atomicAdd(loss_acc, red[0]);
}

// ---------------- K4: emb_sum scatter via per-channel LDS histogram ----------------
__global__ __launch_bounds__(256) void embsum_kernel(
    const float* __restrict__ z, const int* __restrict__ idx_ws,
    float* __restrict__ emb_sum) {
  __shared__ float hist[NE];
  int t = threadIdx.x;
  #pragma unroll
  for (int i = t; i < NE; i += 256) hist[i] = 0.0f;
  __syncthreads();

  int c     = blockIdx.x & 255;
  int chunk = blockIdx.x >> 8;   // 0..7
  int base  = chunk << 14;       // *16384

  for (int i = t; i < 16384; i += 256) {
    int n  = base + i;
    int b  = n >> 12;
    int hw = n & 4095;
    float v = z[(((size_t)(b << 8) + c) << 12) + hw];
    atomicAdd(&hist[idx_ws[n]], v);
  }
  __syncthreads();

  for (int e = t; e < NE; e += 256)
    atomicAdd(&emb_sum[(e << 8) + c], hist[e]);
}

// ---------------- K5: new_cluster_size + n reduction + loss finalize ----------------
__global__ __launch_bounds__(1024) void ema_cs_kernel(
    const float* __restrict__ cs, const float* __restrict__ counts,
    float* __restrict__ out_ncs, float* __restrict__ n_ws,
    const float* __restrict__ loss_acc, float* __restrict__ loss_out) {
  int e = threadIdx.x;
  float ncs = cs[e] * DECAY + ONE_MINUS_DECAY * counts[e];
  out_ncs[e] = ncs;
  __shared__ float red[1024];
  red[e] = ncs;
  __syncthreads();
  for (int s = 512; s > 0; s >>= 1) {
    if (e < s) red[e] += red[e + s];
    __syncthreads();
  }
  if (e == 0) {
    n_ws[0] = red[0];
    loss_out[0] = loss_acc[0] * 2.0f / (float)ZQ_ELEMS;  // (1+beta)*mse
  }
}

// ---------------- K6: new_embedding_avg + new_embedding ----------------
__global__ __launch_bounds__(256) void ema_emb_kernel(
    const float* __restrict__ eavg, const float* __restrict__ emb_sum,
    const float* __restrict__ ncs, const float* __restrict__ n_ws,
    float* __restrict__ out_eavg, float* __restrict__ out_emb) {
  int i = blockIdx.x * 256 + threadIdx.x;  // 262144 elems
  int e = i >> 8;
  float ea = eavg[i] * DECAY + ONE_MINUS_DECAY * emb_sum[i];
  out_eavg[i] = ea;
  float nv   = n_ws[0];
  float ncse = ncs[e];
  float sm   = (ncse + EPSV) / (nv + (float)NE * EPSV) * nv;
  out_emb[i] = ea / sm;
}

extern "C" void kernel_launch(void* const* d_in, const int* in_sizes, int n_in,
                              void* d_out, int out_size, void* d_ws, size_t ws_size,
                              hipStream_t stream) {
  const float* z    = (const float*)d_in[0];  // [32,256,64,64]
  const float* emb  = (const float*)d_in[1];  // [1024,256]
  const float* eavg = (const float*)d_in[2];  // [1024,256]
  const float* cs   = (const float*)d_in[3];  // [1024]

  float* out = (float*)d_out;
  float* out_zq   = out;                         // 33554432
  float* out_loss = out + 33554432;              // 1
  float* out_idx  = out + 33554433;              // 131072
  float* out_emb  = out + 33685505;              // 262144
  float* out_eavg = out + 33947649;              // 262144
  float* out_ncs  = out + 34209793;              // 1024

  float* ws       = (float*)d_ws;
  float* emb_sum  = ws;                          // 262144
  float* counts   = ws + 262144;                 // 1024
  float* loss_acc = ws + 263168;                 // 1
  float* n_ws     = ws + 263169;                 // 1
  int*   idx_ws   = (int*)(ws + 263170);         // 131072 ints
  float* enorm    = ws + 263170 + 131072;        // 1024

  hipMemsetAsync(ws, 0, (size_t)263170 * sizeof(float), stream);

  enorm_kernel<<<NE / 4, 256, 0, stream>>>(emb, enorm);
  argmin_kernel<<<NVEC / 256, 256, 0, stream>>>(z, emb, enorm, idx_ws, out_idx, counts);
  zq_loss_kernel<<<2048, 256, 0, stream>>>(z, emb, idx_ws, out_zq, loss_acc);
  embsum_kernel<<<2048, 256, 0, stream>>>(z, idx_ws, emb_sum);
  ema_cs_kernel<<<1, 1024, 0, stream>>>(cs, counts, out_ncs, n_ws, loss_acc, out_loss);
  ema_emb_kernel<<<262144 / 256, 256, 0, stream>>>(eavg, emb_sum, out_ncs, n_ws, out_eavg, out_emb);
}

// Round 2
// 1871.023 us; speedup vs baseline: 1.6267x; 1.6267x over previous
//
#include <hip/hip_runtime.h>

// Problem constants
#define BATCH 32
#define CDIM 256
#define HW 4096            // 64*64
#define NVEC 131072        // BATCH*HW
#define NE 1024
#define DECAY 0.99f
#define ONE_MINUS_DECAY 0.01f
#define EPSV 1e-5f
#define ZQ_ELEMS 33554432  // BATCH*CDIM*HW

// ---------------- K0: transpose embedding [1024,256] -> embT [256,1024] ----------------
// classic LDS tiled transpose, 32x32 tiles, block (32,8)
__global__ __launch_bounds__(256) void prep_kernel(
    const float* __restrict__ emb, float* __restrict__ embT) {
  __shared__ float tile[32][33];
  int k0 = blockIdx.x * 32;   // 8 k-tiles
  int e0 = blockIdx.y * 32;   // 32 e-tiles
  int tx = threadIdx.x;       // 0..31
  int ty = threadIdx.y;       // 0..7
  #pragma unroll
  for (int j = 0; j < 32; j += 8)
    tile[ty + j][tx] = emb[(size_t)(e0 + ty + j) * CDIM + k0 + tx];
  __syncthreads();
  #pragma unroll
  for (int j = 0; j < 32; j += 8)
    embT[(size_t)(k0 + ty + j) * NE + e0 + tx] = tile[tx][ty + j];
}

// ---------------- K1: embedding row squared norms ----------------
__global__ __launch_bounds__(256) void enorm_kernel(
    const float* __restrict__ emb, float* __restrict__ enorm) {
  int gid  = blockIdx.x * 256 + threadIdx.x;
  int e    = gid >> 6;          // wave index = embedding row
  int lane = threadIdx.x & 63;
  const float4* row = (const float4*)(emb + ((size_t)e << 8));
  float4 v = row[lane];
  float s = v.x * v.x + v.y * v.y + v.z * v.z + v.w * v.w;
  #pragma unroll
  for (int off = 32; off > 0; off >>= 1) s += __shfl_down(s, off);
  if (lane == 0) enorm[e] = s;
}

// ---------------- K2: argmin over codebook + counts + idx outputs ----------------
// thread = one z-vector. ET=128 accumulators in VGPRs; embT rows are
// wave-uniform contiguous -> s_load_dwordx16 on the scalar pipe; inner body
// is a single v_fmac_f32 with SGPR operand. 8 passes over z (1.07 GB cached).
#define ET 128
__global__ __launch_bounds__(256) void argmin_kernel(
    const float* __restrict__ z, const float* __restrict__ embT,
    const float* __restrict__ enorm, int* __restrict__ idx_ws,
    float* __restrict__ idx_out, float* __restrict__ counts) {
  int n  = blockIdx.x * 256 + threadIdx.x;
  int b  = n >> 12;
  int hw = n & 4095;
  const float* zp = z + ((size_t)b << 20) + hw;  // element k at zp[k*4096]

  float best = 3.0e38f;
  int bi = 0;

  #pragma unroll 1
  for (int et = 0; et < NE; et += ET) {
    float acc[ET];
    #pragma unroll
    for (int e = 0; e < ET; ++e) acc[e] = 0.0f;

    #pragma unroll 2
    for (int k = 0; k < CDIM; ++k) {
      float zk = zp[(size_t)k << 12];
      const float* row = embT + ((size_t)k << 10) + et;  // wave-uniform
      #pragma unroll
      for (int e = 0; e < ET; ++e)
        acc[e] = fmaf(zk, row[e], acc[e]);
    }

    #pragma unroll
    for (int e = 0; e < ET; ++e) {
      float d = enorm[et + e] - 2.0f * acc[e];
      bool c = d < best;                 // strict < : first-min tie-break
      bi   = c ? (et + e) : bi;
      best = c ? d : best;
    }
  }

  idx_ws[n] = bi;
  idx_out[n] = (float)bi;
  atomicAdd(&counts[bi], 1.0f);
}

// ---------------- K3: z_q gather (NCHW) + loss partial, float4 ----------------
__global__ __launch_bounds__(256) void zq_loss_kernel(
    const float* __restrict__ z, const float* __restrict__ emb,
    const int* __restrict__ idx_ws, float* __restrict__ zq_out,
    float* __restrict__ loss_acc) {
  int stride = gridDim.x * 256;
  float lsum = 0.0f;
  const float4* z4 = (const float4*)z;
  const int4* idx4 = (const int4*)idx_ws;
  float4* zq4 = (float4*)zq_out;
  for (int o4 = blockIdx.x * 256 + threadIdx.x; o4 < ZQ_ELEMS / 4; o4 += stride) {
    int o  = o4 << 2;
    int hw = o & 4095;
    int c  = (o >> 12) & 255;
    int b  = o >> 20;
    int4 id = idx4[((b << 12) | hw) >> 2];
    float4 zv = z4[o4];
    float4 q;
    q.x = emb[((size_t)id.x << 8) + c];
    q.y = emb[((size_t)id.y << 8) + c];
    q.z = emb[((size_t)id.z << 8) + c];
    q.w = emb[((size_t)id.w << 8) + c];
    zq4[o4] = q;
    float dx = q.x - zv.x, dy = q.y - zv.y, dz = q.z - zv.z, dw = q.w - zv.w;
    lsum += dx * dx + dy * dy + dz * dz + dw * dw;
  }
  __shared__ float red[256];
  red[threadIdx.x] = lsum;
  __syncthreads();
  for (int s = 128; s > 0; s >>= 1) {
    if (threadIdx.x < s) red[threadIdx.x] += red[threadIdx.x + s];
    __syncthreads();
  }
  if (threadIdx.x == 0) atomicAdd(loss_acc, red[0]);
}

// ---------------- K4: emb_sum scatter via per-channel LDS histogram ----------------
__global__ __launch_bounds__(256) void embsum_kernel(
    const float* __restrict__ z, const int* __restrict__ idx_ws,
    float* __restrict__ emb_sum) {
  __shared__ float hist[NE];
  int t = threadIdx.x;
  #pragma unroll
  for (int i = t; i < NE; i += 256) hist[i] = 0.0f;
  __syncthreads();

  int c     = blockIdx.x & 255;
  int chunk = blockIdx.x >> 8;   // 0..7
  int base  = chunk << 14;       // *16384 vectors per chunk

  const int4* idx4 = (const int4*)idx_ws;
  for (int i4 = t; i4 < 4096; i4 += 256) {
    int n0 = base + (i4 << 2);
    int b  = n0 >> 12;
    int hw = n0 & 4095;
    float4 v = *(const float4*)(z + ((((size_t)(b << 8) + c) << 12) + hw));
    int4 id = idx4[n0 >> 2];
    atomicAdd(&hist[id.x], v.x);
    atomicAdd(&hist[id.y], v.y);
    atomicAdd(&hist[id.z], v.z);
    atomicAdd(&hist[id.w], v.w);
  }
  __syncthreads();

  for (int e = t; e < NE; e += 256)
    atomicAdd(&emb_sum[(e << 8) + c], hist[e]);
}

// ---------------- K5: new_cluster_size + n reduction + loss finalize ----------------
__global__ __launch_bounds__(1024) void ema_cs_kernel(
    const float* __restrict__ cs, const float* __restrict__ counts,
    float* __restrict__ out_ncs, float* __restrict__ n_ws,
    const float* __restrict__ loss_acc, float* __restrict__ loss_out) {
  int e = threadIdx.x;
  float ncs = cs[e] * DECAY + ONE_MINUS_DECAY * counts[e];
  out_ncs[e] = ncs;
  __shared__ float red[1024];
  red[e] = ncs;
  __syncthreads();
  for (int s = 512; s > 0; s >>= 1) {
    if (e < s) red[e] += red[e + s];
    __syncthreads();
  }
  if (e == 0) {
    n_ws[0] = red[0];
    loss_out[0] = loss_acc[0] * 2.0f / (float)ZQ_ELEMS;  // (1+beta)*mse
  }
}

// ---------------- K6: new_embedding_avg + new_embedding ----------------
__global__ __launch_bounds__(256) void ema_emb_kernel(
    const float* __restrict__ eavg, const float* __restrict__ emb_sum,
    const float* __restrict__ ncs, const float* __restrict__ n_ws,
    float* __restrict__ out_eavg, float* __restrict__ out_emb) {
  int i = blockIdx.x * 256 + threadIdx.x;  // 262144 elems
  int e = i >> 8;
  float ea = eavg[i] * DECAY + ONE_MINUS_DECAY * emb_sum[i];
  out_eavg[i] = ea;
  float nv   = n_ws[0];
  float ncse = ncs[e];
  float sm   = (ncse + EPSV) / (nv + (float)NE * EPSV) * nv;
  out_emb[i] = ea / sm;
}

extern "C" void kernel_launch(void* const* d_in, const int* in_sizes, int n_in,
                              void* d_out, int out_size, void* d_ws, size_t ws_size,
                              hipStream_t stream) {
  const float* z    = (const float*)d_in[0];  // [32,256,64,64]
  const float* emb  = (const float*)d_in[1];  // [1024,256]
  const float* eavg = (const float*)d_in[2];  // [1024,256]
  const float* cs   = (const float*)d_in[3];  // [1024]

  float* out = (float*)d_out;
  float* out_zq   = out;                         // 33554432
  float* out_loss = out + 33554432;              // 1
  float* out_idx  = out + 33554433;              // 131072
  float* out_emb  = out + 33685505;              // 262144
  float* out_eavg = out + 33947649;              // 262144
  float* out_ncs  = out + 34209793;              // 1024

  float* ws       = (float*)d_ws;
  float* emb_sum  = ws;                          // 262144
  float* counts   = ws + 262144;                 // 1024
  float* loss_acc = ws + 263168;                 // 1
  float* n_ws     = ws + 263169;                 // 1
  int*   idx_ws   = (int*)(ws + 263170);         // 131072 ints
  float* enorm    = ws + 263170 + 131072;        // 1024

  // embT scratch lives at the head of out_zq: argmin reads it, then
  // zq_loss_kernel overwrites the whole region. (avoids growing ws)
  float* embT = out_zq;                          // 262144 floats

  hipMemsetAsync(ws, 0, (size_t)263170 * sizeof(float), stream);

  dim3 tb(32, 8);
  dim3 tg(CDIM / 32, NE / 32);
  prep_kernel<<<tg, tb, 0, stream>>>(emb, embT);
  enorm_kernel<<<NE / 4, 256, 0, stream>>>(emb, enorm);
  argmin_kernel<<<NVEC / 256, 256, 0, stream>>>(z, embT, enorm, idx_ws, out_idx, counts);
  zq_loss_kernel<<<2048, 256, 0, stream>>>(z, emb, idx_ws, out_zq, loss_acc);
  embsum_kernel<<<2048, 256, 0, stream>>>(z, idx_ws, emb_sum);
  ema_cs_kernel<<<1, 1024, 0, stream>>>(cs, counts, out_ncs, n_ws, loss_acc, out_loss);
  ema_emb_kernel<<<262144 / 256, 256, 0, stream>>>(eavg, emb_sum, out_ncs, n_ws, out_eavg, out_emb);
}